// Round 14
// baseline (33.842 us; speedup 1.0000x reference)
//
#include <hip/hip_runtime.h>

#define H 1024
#define W 1024
#define NPIX (H * W)
#define NIMG 12
#define TOT (NIMG * NPIX)
#define NWORDS (TOT / 64)   /* 196608 fg-mask words (64 px each) */
#define WPR 16              /* mask words per image row */
#define WPI (NPIX / 64)     /* mask words per image */

#define RSTRIP 8                      /* rows per block strip */
#define NBLK (NIMG * (H / RSTRIP))    /* 1536 gm blocks */

typedef unsigned long long ull;

// Constants computed in double then demoted to float, matching Python/JAX.
__device__ __constant__ float C_HALF = (float)(0.5 * (1.0 / 1023.0));
__device__ __constant__ float C_FOUR = (float)(4.0 * (1.0 / 1023.0));
__device__ __constant__ float C_ONE  = (float)(1.0 * (1.0 / 1023.0));
#define SCALE 255.75f  /* 1023/4, exact */

// static component select (folds to a register pick under full unroll)
#define COMP(v, k) ((k) == 0 ? (v).x : (k) == 1 ? (v).y : (k) == 2 ? (v).z : (v).w)

// --------------------------------------------------------------- gm (dense)
// R12 structure (shfl horizontal halos, 1 load + 1 store per row) at
// RSTRIP=8: amortizes the 6-row vertical halo init over 8 rows ->
// ~8.6M thread-level VMEM requests (the confirmed cost law).
__global__ __launch_bounds__(256) void gm_kernel(const float* __restrict__ in,
                                                 float* __restrict__ out,
                                                 ull* __restrict__ mask) {
    int bid = blockIdx.x;
    // XCD-chunked swizzle: contiguous strips stay on one XCD's L2 (1536%8==0)
    int wblk = (bid & 7) * (NBLK / 8) + (bid >> 3);
    int img   = wblk >> 7;            // 128 strips per image
    int strip = wblk & 127;
    int y0 = strip * RSTRIP;
    int t  = threadIdx.x;             // float4-column, 256 per row
    int x0 = t << 2;
    const float* im = in + ((size_t)img << 20);
    float* ob = out + ((size_t)img << 20);
    int lane = t & 63;
    bool e0  = (lane == 0);
    bool e63 = (lane == 63);

    const float4 z4 = make_float4(0.f, 0.f, 0.f, 0.f);
    float4 win[7];                    // rows y-3 .. y+3 of this column
    #pragma unroll
    for (int j = 0; j < 6; ++j) {
        int yy = y0 - 3 + j;
        win[j] = (yy >= 0 && yy < H) ? *(const float4*)(im + yy * W + x0) : z4;
    }

    #pragma unroll
    for (int i = 0; i < RSTRIP; ++i) {
        int y = y0 + i;
        int yl = y + 3;
        win[6] = (yl < H) ? *(const float4*)(im + yl * W + x0) : z4;
        float4 B = win[3];

        // one predicated load serves both wave-edge lanes (lane0: x0-4,
        // lane63: x0+4); interior lanes get halos via shfl below.
        float4 edge = z4;
        if ((e0 & (x0 >= 4)) | (e63 & (x0 < 1020))) {
            edge = *(const float4*)(im + y * W + (e0 ? x0 - 4 : x0 + 4));
        }
        // left halo: columns x0-3..x0-1 = neighbor lane's B.y/.z/.w
        float Ay = __shfl_up(B.y, 1);
        float Az = __shfl_up(B.z, 1);
        float Aw = __shfl_up(B.w, 1);
        if (e0) { Ay = edge.y; Az = edge.z; Aw = edge.w; }
        // right halo: columns x0+4..x0+6 = neighbor lane's B.x/.y/.z
        float Cx = __shfl_down(B.x, 1);
        float Cy = __shfl_down(B.y, 1);
        float Cz = __shfl_down(B.z, 1);
        if (e63) { Cx = edge.x; Cy = edge.y; Cz = edge.z; }

        // wnd[j] = column x0-4+j (wnd[0]/wnd[11] unused by k=0..3)
        float wnd[12] = {0.0f, Ay, Az, Aw, B.x, B.y, B.z, B.w,
                         Cx, Cy, Cz, 0.0f};

        unsigned nib = 0;
        #pragma unroll
        for (int k = 0; k < 4; ++k) {
            // axis=1 (x): d(k') = col(x-k') - col(x+k'), zero fill
            float g1 = wnd[k + 3] - wnd[k + 5];
            float a = fabsf(g1);
            bool arange = (a <= C_FOUR) & (a > C_ONE);
            float gx = 0.0f;
            if (__any(arange)) {
                float g2 = wnd[k + 2] - wnd[k + 6];
                float g3 = wnd[k + 1] - wnd[k + 7];
                float gmer = (g1 + g2 + g3) / 3.0f;
                bool keep = (fabsf(gmer - g1) <= C_HALF) & arange;
                gx = keep ? a : 0.0f;
            }
            // axis=0 (y)
            g1 = COMP(win[2], k) - COMP(win[4], k);
            a = fabsf(g1);
            arange = (a <= C_FOUR) & (a > C_ONE);
            float gy = 0.0f;
            if (__any(arange)) {
                float g2 = COMP(win[1], k) - COMP(win[5], k);
                float g3 = COMP(win[0], k) - COMP(win[6], k);
                float gmer = (g1 + g2 + g3) / 3.0f;
                bool keep = (fabsf(gmer - g1) <= C_HALF) & arange;
                gy = keep ? a : 0.0f;
            }

            float gmv = fmaxf(gx, gy) * SCALE;
            nib |= (unsigned)(gmv > 1.0f) << k;
        }

        // zero output row segment (sparse_final rewrites the few nonzeros)
        *(float4*)(ob + y * W + x0) = z4;

        // mask words via 32-bit butterfly: 8 lanes x 4 bits per 32-bit group,
        // then one cross-halfword shfl to assemble the 64-px word.
        unsigned v32 = nib << ((lane & 7) << 2);
        v32 |= __shfl_xor((int)v32, 1);
        v32 |= __shfl_xor((int)v32, 2);
        v32 |= __shfl_xor((int)v32, 4);
        unsigned hi = (unsigned)__shfl_xor((int)v32, 8);
        if ((lane & 15) == 0) {
            mask[((size_t)img << 14) + (y << 4) + (t >> 4)] =
                (ull)v32 | ((ull)hi << 32);
        }

        // slide window
        #pragma unroll
        for (int j = 0; j < 6; ++j) win[j] = win[j + 1];
    }
}

// ----------------------------------------------- sparse label/count init
__global__ __launch_bounds__(256) void init_words(const ull* __restrict__ mask,
                                                  int* __restrict__ labels,
                                                  int* __restrict__ counts) {
    int w = blockIdx.x * blockDim.x + threadIdx.x;
    ull m = mask[w];
    if (!m) return;
    int img = w >> 14;
    int pbase = (w & (WPI - 1)) << 6;
    int* L = labels + ((size_t)img << 20);
    int* C = counts + ((size_t)img << 20);
    while (m) {
        int b = __builtin_ctzll(m);
        m &= m - 1;
        int p = pbase + b;
        L[p] = p;
        C[p] = 0;
    }
}

// ------------------------------------------------------------- union-find
__device__ __forceinline__ int find_root(int* L, int a) {
    int l = L[a];
    while (l != a) { a = l; l = L[a]; }
    return a;
}

__device__ __forceinline__ void unite(int* L, int a, int b) {
    while (true) {
        a = find_root(L, a);
        b = find_root(L, b);
        if (a == b) return;
        if (a > b) { int t = a; a = b; b = t; }
        int old = atomicMin(&L[b], a);
        if (old == b) return;
        b = old;
    }
}

// ------------------------------------------- word-based (sparse) CCL kernels
__global__ __launch_bounds__(256) void merge_words(const ull* __restrict__ mask,
                                                   int* __restrict__ labels) {
    int w = blockIdx.x * blockDim.x + threadIdx.x;
    ull m = mask[w];
    if (!m) return;
    int img = w >> 14;
    int wp  = w & (WPI - 1);
    int row = wp >> 4, colw = wp & 15;
    int* L = labels + ((size_t)img << 20);
    bool hasS = row < H - 1, hasE = colw < 15, hasW = colw > 0;
    ull mS   = hasS ? mask[w + WPR] : 0ull;
    ull mE1  = hasE ? mask[w + 1] : 0ull;
    ull mSWw = (hasS && hasW) ? mask[w + WPR - 1] : 0ull;
    ull mSEw = (hasS && hasE) ? mask[w + WPR + 1] : 0ull;
    ull fgE  = (m >> 1) | (mE1 << 63);
    ull fgS  = mS;
    ull fgSW = (mS << 1) | (mSWw >> 63);
    ull fgSE = (mS >> 1) | (mSEw << 63);
    int pbase = wp << 6;
    ull t = m;
    while (t) {
        int b = __builtin_ctzll(t);
        t &= t - 1;
        int p = pbase + b;
        ull bit = 1ull << b;
        if (fgE & bit)  unite(L, p, p + 1);
        if (fgSW & bit) unite(L, p, p + W - 1);
        if (fgS & bit)  unite(L, p, p + W);
        if (fgSE & bit) unite(L, p, p + W + 1);
    }
}

__global__ __launch_bounds__(256) void count_words(const ull* __restrict__ mask,
                                                   int* __restrict__ labels,
                                                   int* __restrict__ counts) {
    int w = blockIdx.x * blockDim.x + threadIdx.x;
    ull m = mask[w];
    if (!m) return;
    int img = w >> 14;
    int wp  = w & (WPI - 1);
    int row = wp >> 4, colw = wp & 15;
    int* L = labels + ((size_t)img << 20);
    int* C = counts + ((size_t)img << 20);
    ull mN  = (row > 0)     ? mask[w - WPR] : 0ull;
    ull mS  = (row < H - 1) ? mask[w + WPR] : 0ull;
    ull mE1 = (colw < 15)   ? mask[w + 1]   : 0ull;
    ull mWw = (colw > 0)    ? mask[w - 1]   : 0ull;
    ull fgE = (m >> 1) | (mE1 << 63);
    ull fgW = (m << 1) | (mWw >> 63);
    ull boundary = m & ~(mN & mS & fgE & fgW);
    int pbase = wp << 6;
    while (boundary) {
        int b = __builtin_ctzll(boundary);
        boundary &= boundary - 1;
        int p = pbase + b;
        int r = find_root(L, p);
        L[p] = r;                 // flatten boundary pixels (read by final)
        atomicAdd(&C[r], 1);
    }
}

// --------------------------------------------------- sparse final (dm eval)
// Recompute gm bitwise-identically at (y,x); zero-fill at image edges.
__device__ float gm_eval(const float* __restrict__ im, int y, int x) {
    int p = y * W + x;
    float xm1 = (x >= 1)     ? im[p - 1] : 0.0f;
    float xp1 = (x < W - 1)  ? im[p + 1] : 0.0f;
    float xm2 = (x >= 2)     ? im[p - 2] : 0.0f;
    float xp2 = (x < W - 2)  ? im[p + 2] : 0.0f;
    float xm3 = (x >= 3)     ? im[p - 3] : 0.0f;
    float xp3 = (x < W - 3)  ? im[p + 3] : 0.0f;
    float g1 = xm1 - xp1;
    float g2 = xm2 - xp2;
    float g3 = xm3 - xp3;
    float gmer = (g1 + g2 + g3) / 3.0f;
    float a = fabsf(g1);
    bool keep = (fabsf(gmer - g1) <= C_HALF) & (a <= C_FOUR) & (a > C_ONE);
    float gx = keep ? a : 0.0f;

    float ym1 = (y >= 1)    ? im[p - W]     : 0.0f;
    float yp1 = (y < H - 1) ? im[p + W]     : 0.0f;
    float ym2 = (y >= 2)    ? im[p - 2 * W] : 0.0f;
    float yp2 = (y < H - 2) ? im[p + 2 * W] : 0.0f;
    float ym3 = (y >= 3)    ? im[p - 3 * W] : 0.0f;
    float yp3 = (y < H - 3) ? im[p + 3 * W] : 0.0f;
    g1 = ym1 - yp1;
    g2 = ym2 - yp2;
    g3 = ym3 - yp3;
    gmer = (g1 + g2 + g3) / 3.0f;
    a = fabsf(g1);
    keep = (fabsf(gmer - g1) <= C_HALF) & (a <= C_FOUR) & (a > C_ONE);
    float gy = keep ? a : 0.0f;

    return fmaxf(gx, gy) * SCALE;
}

__device__ __forceinline__ float gmz(const float* __restrict__ im, int y, int x) {
    if ((unsigned)y >= H || (unsigned)x >= W) return 0.0f;  // zero fill
    return gm_eval(im, y, x);
}

__global__ __launch_bounds__(256) void sparse_final(const float* __restrict__ in,
                                                    const ull* __restrict__ mask,
                                                    const int* __restrict__ labels,
                                                    const int* __restrict__ counts,
                                                    float* __restrict__ out) {
    #pragma clang fp contract(off)
    int w = blockIdx.x * blockDim.x + threadIdx.x;
    ull m = mask[w];
    if (!m) return;
    int img = w >> 14;
    int wp  = w & (WPI - 1);
    int row = wp >> 4, colw = wp & 15;
    const float* im = in + ((size_t)img << 20);
    const int* L = labels + ((size_t)img << 20);
    const int* C = counts + ((size_t)img << 20);
    ull mN  = (row > 0)     ? mask[w - WPR] : 0ull;
    ull mS  = (row < H - 1) ? mask[w + WPR] : 0ull;
    ull mE1 = (colw < 15)   ? mask[w + 1]   : 0ull;
    ull mWw = (colw > 0)    ? mask[w - 1]   : 0ull;
    ull fgE = (m >> 1) | (mE1 << 63);
    ull fgW = (m << 1) | (mWw >> 63);
    ull boundary = m & ~(mN & mS & fgE & fgW);
    int pbase = wp << 6;
    while (boundary) {
        int b = __builtin_ctzll(boundary);
        boundary &= boundary - 1;
        int p = pbase + b;
        int c = C[L[p]];
        if (c <= 21) continue;          // lm == 0 -> out stays 0
        int y = p >> 10, x = p & 1023;

        // directmask at (y,x): 3x3 reflect blur of gradient products
        float sxx = 0.0f, syy = 0.0f, sxy = 0.0f;
        #pragma unroll
        for (int di = -1; di <= 1; ++di) {
            int r = y + di;
            if (r < 0) r = -r;
            if (r >= H) r = 2 * H - 2 - r;
            #pragma unroll
            for (int dj = -1; dj <= 1; ++dj) {
                int cc = x + dj;
                if (cc < 0) cc = -cc;
                if (cc >= W) cc = 2 * W - 2 - cc;
                float gxv = gmz(im, r, cc - 1) - gmz(im, r, cc + 1);
                float gyv = gmz(im, r - 1, cc) - gmz(im, r + 1, cc);
                float txx = gxv * gxv;
                float tyy = gyv * gyv;
                float txy = gxv * gyv;
                sxx = sxx + txx;
                syy = syy + tyy;
                sxy = sxy + txy;
            }
        }
        sxx /= 9.0f; syy /= 9.0f; sxy /= 9.0f;
        float d = sxx - syy;
        float tmp = sqrtf(d * d + 4.0f * (sxy * sxy));
        float dmv = tmp / (sxx + syy + 1e-16f);

        float gc_ = gm_eval(im, y, x);
        float v = gc_ * dmv * (float)c;
        v = fminf(fmaxf(v, 0.0f), 1.0f);
        out[((size_t)img << 20) + p] = v;
    }
}

// ---------------------------------------------------------------- launch
extern "C" void kernel_launch(void* const* d_in, const int* in_sizes, int n_in,
                              void* d_out, int out_size, void* d_ws, size_t ws_size,
                              hipStream_t stream) {
    const float* base = (const float*)d_in[0];
    float* out = (float*)d_out;

    int* labels = (int*)d_ws;
    int* counts = (int*)((char*)d_ws + (size_t)TOT * 4);
    ull* mask   = (ull*)((char*)d_ws + 2ull * (size_t)TOT * 4);

    dim3 block(256);
    dim3 gridStrips(NBLK);
    dim3 gridWords(NWORDS / 256);

    gm_kernel<<<gridStrips, block, 0, stream>>>(base, out, mask);
    init_words<<<gridWords, block, 0, stream>>>(mask, labels, counts);
    merge_words<<<gridWords, block, 0, stream>>>(mask, labels);
    count_words<<<gridWords, block, 0, stream>>>(mask, labels, counts);
    sparse_final<<<gridWords, block, 0, stream>>>(base, mask, labels, counts, out);
}

// Round 15
// 31.646 us; speedup vs baseline: 1.0694x; 1.0694x over previous
//
#include <hip/hip_runtime.h>

#define H 1024
#define W 1024
#define NPIX (H * W)
#define NIMG 12
#define TOT (NIMG * NPIX)
#define NWORDS (TOT / 64)   /* 196608 fg-mask words (64 px each) */
#define WPR 16              /* mask words per image row */
#define WPI (NPIX / 64)     /* mask words per image */

#define RSTRIP 4                          /* rows per strip */
#define BT 128                            /* gm block threads (2 waves) */
#define NBLK (NIMG * (H / RSTRIP) * 2)    /* 6144 gm blocks (half-width) */

typedef unsigned long long ull;

// Constants computed in double then demoted to float, matching Python/JAX.
__device__ __constant__ float C_HALF = (float)(0.5 * (1.0 / 1023.0));
__device__ __constant__ float C_FOUR = (float)(4.0 * (1.0 / 1023.0));
__device__ __constant__ float C_ONE  = (float)(1.0 * (1.0 / 1023.0));
#define SCALE 255.75f  /* 1023/4, exact */

// static component select (folds to a register pick under full unroll)
#define COMP(v, k) ((k) == 0 ? (v).x : (k) == 1 ? (v).y : (k) == 2 ? (v).z : (v).w)

// --------------------------------------------------------------- gm (dense)
// R12 structure (shfl horizontal halos, RSTRIP=4) with 128-thread blocks:
// finer residency backfill (2-wave granules) flattens the second-round
// occupancy tail (time ~ requests / resident-waves). Labels/counts init
// folded back inline (R7-characterized, saves one dispatch + mask pass).
__global__ __launch_bounds__(BT) void gm_kernel(const float* __restrict__ in,
                                                float* __restrict__ out,
                                                ull* __restrict__ mask,
                                                int* __restrict__ labels,
                                                int* __restrict__ counts) {
    int bid = blockIdx.x;
    // XCD-chunked swizzle: contiguous blocks stay on one XCD's L2 (6144%8==0)
    int wblk = (bid & 7) * (NBLK / 8) + (bid >> 3);
    int img   = wblk >> 9;            // 512 blocks per image
    int rem   = wblk & 511;
    int strip = rem >> 1;
    int xbase = (rem & 1) << 9;       // 0 or 512
    int y0 = strip * RSTRIP;
    int t  = threadIdx.x;             // 128 threads: half-row of quads
    int x0 = xbase + (t << 2);
    const float* im = in + ((size_t)img << 20);
    float* ob = out + ((size_t)img << 20);
    int* Lb = labels + ((size_t)img << 20);
    int* Cb = counts + ((size_t)img << 20);
    int lane = t & 63;
    bool e0  = (lane == 0);
    bool e63 = (lane == 63);

    const float4 z4 = make_float4(0.f, 0.f, 0.f, 0.f);
    float4 win[7];                    // rows y-3 .. y+3 of this column
    #pragma unroll
    for (int j = 0; j < 6; ++j) {
        int yy = y0 - 3 + j;
        win[j] = (yy >= 0 && yy < H) ? *(const float4*)(im + yy * W + x0) : z4;
    }

    #pragma unroll
    for (int i = 0; i < RSTRIP; ++i) {
        int y = y0 + i;
        int yl = y + 3;
        win[6] = (yl < H) ? *(const float4*)(im + yl * W + x0) : z4;
        float4 B = win[3];

        // one predicated load serves both wave-edge lanes (lane0: x0-4,
        // lane63: x0+4); interior lanes get halos via shfl below.
        float4 edge = z4;
        if ((e0 & (x0 >= 4)) | (e63 & (x0 < 1020))) {
            edge = *(const float4*)(im + y * W + (e0 ? x0 - 4 : x0 + 4));
        }
        // left halo: columns x0-3..x0-1 = neighbor lane's B.y/.z/.w
        float Ay = __shfl_up(B.y, 1);
        float Az = __shfl_up(B.z, 1);
        float Aw = __shfl_up(B.w, 1);
        if (e0) { Ay = edge.y; Az = edge.z; Aw = edge.w; }
        // right halo: columns x0+4..x0+6 = neighbor lane's B.x/.y/.z
        float Cx = __shfl_down(B.x, 1);
        float Cy = __shfl_down(B.y, 1);
        float Cz = __shfl_down(B.z, 1);
        if (e63) { Cx = edge.x; Cy = edge.y; Cz = edge.z; }

        // wnd[j] = column x0-4+j (wnd[0]/wnd[11] unused by k=0..3)
        float wnd[12] = {0.0f, Ay, Az, Aw, B.x, B.y, B.z, B.w,
                         Cx, Cy, Cz, 0.0f};

        unsigned nib = 0;
        #pragma unroll
        for (int k = 0; k < 4; ++k) {
            // axis=1 (x): d(k') = col(x-k') - col(x+k'), zero fill
            float g1 = wnd[k + 3] - wnd[k + 5];
            float a = fabsf(g1);
            bool arange = (a <= C_FOUR) & (a > C_ONE);
            float gx = 0.0f;
            if (__any(arange)) {
                float g2 = wnd[k + 2] - wnd[k + 6];
                float g3 = wnd[k + 1] - wnd[k + 7];
                float gmer = (g1 + g2 + g3) / 3.0f;
                bool keep = (fabsf(gmer - g1) <= C_HALF) & arange;
                gx = keep ? a : 0.0f;
            }
            // axis=0 (y)
            g1 = COMP(win[2], k) - COMP(win[4], k);
            a = fabsf(g1);
            arange = (a <= C_FOUR) & (a > C_ONE);
            float gy = 0.0f;
            if (__any(arange)) {
                float g2 = COMP(win[1], k) - COMP(win[5], k);
                float g3 = COMP(win[0], k) - COMP(win[6], k);
                float gmer = (g1 + g2 + g3) / 3.0f;
                bool keep = (fabsf(gmer - g1) <= C_HALF) & arange;
                gy = keep ? a : 0.0f;
            }

            float gmv = fmaxf(gx, gy) * SCALE;
            bool fg = gmv > 1.0f;
            if (fg) {
                int p = y * W + x0 + k;
                Lb[p] = p;
                Cb[p] = 0;
            }
            nib |= (unsigned)fg << k;
        }

        // zero output row segment (sparse_final rewrites the few nonzeros)
        *(float4*)(ob + y * W + x0) = z4;

        // mask words via 32-bit butterfly: 8 lanes x 4 bits per 32-bit group,
        // then one cross-halfword shfl to assemble the 64-px word.
        unsigned v32 = nib << ((lane & 7) << 2);
        v32 |= __shfl_xor((int)v32, 1);
        v32 |= __shfl_xor((int)v32, 2);
        v32 |= __shfl_xor((int)v32, 4);
        unsigned hi = (unsigned)__shfl_xor((int)v32, 8);
        if ((lane & 15) == 0) {
            mask[((size_t)img << 14) + (y << 4) + (x0 >> 6)] =
                (ull)v32 | ((ull)hi << 32);
        }

        // slide window
        #pragma unroll
        for (int j = 0; j < 6; ++j) win[j] = win[j + 1];
    }
}

// ------------------------------------------------------------- union-find
__device__ __forceinline__ int find_root(int* L, int a) {
    int l = L[a];
    while (l != a) { a = l; l = L[a]; }
    return a;
}

__device__ __forceinline__ void unite(int* L, int a, int b) {
    while (true) {
        a = find_root(L, a);
        b = find_root(L, b);
        if (a == b) return;
        if (a > b) { int t = a; a = b; b = t; }
        int old = atomicMin(&L[b], a);
        if (old == b) return;
        b = old;
    }
}

// ------------------------------------------- word-based (sparse) CCL kernels
__global__ __launch_bounds__(256) void merge_words(const ull* __restrict__ mask,
                                                   int* __restrict__ labels) {
    int w = blockIdx.x * blockDim.x + threadIdx.x;
    ull m = mask[w];
    if (!m) return;
    int img = w >> 14;
    int wp  = w & (WPI - 1);
    int row = wp >> 4, colw = wp & 15;
    int* L = labels + ((size_t)img << 20);
    bool hasS = row < H - 1, hasE = colw < 15, hasW = colw > 0;
    ull mS   = hasS ? mask[w + WPR] : 0ull;
    ull mE1  = hasE ? mask[w + 1] : 0ull;
    ull mSWw = (hasS && hasW) ? mask[w + WPR - 1] : 0ull;
    ull mSEw = (hasS && hasE) ? mask[w + WPR + 1] : 0ull;
    ull fgE  = (m >> 1) | (mE1 << 63);
    ull fgS  = mS;
    ull fgSW = (mS << 1) | (mSWw >> 63);
    ull fgSE = (mS >> 1) | (mSEw << 63);
    int pbase = wp << 6;
    ull t = m;
    while (t) {
        int b = __builtin_ctzll(t);
        t &= t - 1;
        int p = pbase + b;
        ull bit = 1ull << b;
        if (fgE & bit)  unite(L, p, p + 1);
        if (fgSW & bit) unite(L, p, p + W - 1);
        if (fgS & bit)  unite(L, p, p + W);
        if (fgSE & bit) unite(L, p, p + W + 1);
    }
}

__global__ __launch_bounds__(256) void count_words(const ull* __restrict__ mask,
                                                   int* __restrict__ labels,
                                                   int* __restrict__ counts) {
    int w = blockIdx.x * blockDim.x + threadIdx.x;
    ull m = mask[w];
    if (!m) return;
    int img = w >> 14;
    int wp  = w & (WPI - 1);
    int row = wp >> 4, colw = wp & 15;
    int* L = labels + ((size_t)img << 20);
    int* C = counts + ((size_t)img << 20);
    ull mN  = (row > 0)     ? mask[w - WPR] : 0ull;
    ull mS  = (row < H - 1) ? mask[w + WPR] : 0ull;
    ull mE1 = (colw < 15)   ? mask[w + 1]   : 0ull;
    ull mWw = (colw > 0)    ? mask[w - 1]   : 0ull;
    ull fgE = (m >> 1) | (mE1 << 63);
    ull fgW = (m << 1) | (mWw >> 63);
    ull boundary = m & ~(mN & mS & fgE & fgW);
    int pbase = wp << 6;
    while (boundary) {
        int b = __builtin_ctzll(boundary);
        boundary &= boundary - 1;
        int p = pbase + b;
        int r = find_root(L, p);
        L[p] = r;                 // flatten boundary pixels (read by final)
        atomicAdd(&C[r], 1);
    }
}

// --------------------------------------------------- sparse final (dm eval)
// Recompute gm bitwise-identically at (y,x); zero-fill at image edges.
__device__ float gm_eval(const float* __restrict__ im, int y, int x) {
    int p = y * W + x;
    float xm1 = (x >= 1)     ? im[p - 1] : 0.0f;
    float xp1 = (x < W - 1)  ? im[p + 1] : 0.0f;
    float xm2 = (x >= 2)     ? im[p - 2] : 0.0f;
    float xp2 = (x < W - 2)  ? im[p + 2] : 0.0f;
    float xm3 = (x >= 3)     ? im[p - 3] : 0.0f;
    float xp3 = (x < W - 3)  ? im[p + 3] : 0.0f;
    float g1 = xm1 - xp1;
    float g2 = xm2 - xp2;
    float g3 = xm3 - xp3;
    float gmer = (g1 + g2 + g3) / 3.0f;
    float a = fabsf(g1);
    bool keep = (fabsf(gmer - g1) <= C_HALF) & (a <= C_FOUR) & (a > C_ONE);
    float gx = keep ? a : 0.0f;

    float ym1 = (y >= 1)    ? im[p - W]     : 0.0f;
    float yp1 = (y < H - 1) ? im[p + W]     : 0.0f;
    float ym2 = (y >= 2)    ? im[p - 2 * W] : 0.0f;
    float yp2 = (y < H - 2) ? im[p + 2 * W] : 0.0f;
    float ym3 = (y >= 3)    ? im[p - 3 * W] : 0.0f;
    float yp3 = (y < H - 3) ? im[p + 3 * W] : 0.0f;
    g1 = ym1 - yp1;
    g2 = ym2 - yp2;
    g3 = ym3 - yp3;
    gmer = (g1 + g2 + g3) / 3.0f;
    a = fabsf(g1);
    keep = (fabsf(gmer - g1) <= C_HALF) & (a <= C_FOUR) & (a > C_ONE);
    float gy = keep ? a : 0.0f;

    return fmaxf(gx, gy) * SCALE;
}

__device__ __forceinline__ float gmz(const float* __restrict__ im, int y, int x) {
    if ((unsigned)y >= H || (unsigned)x >= W) return 0.0f;  // zero fill
    return gm_eval(im, y, x);
}

__global__ __launch_bounds__(256) void sparse_final(const float* __restrict__ in,
                                                    const ull* __restrict__ mask,
                                                    const int* __restrict__ labels,
                                                    const int* __restrict__ counts,
                                                    float* __restrict__ out) {
    #pragma clang fp contract(off)
    int w = blockIdx.x * blockDim.x + threadIdx.x;
    ull m = mask[w];
    if (!m) return;
    int img = w >> 14;
    int wp  = w & (WPI - 1);
    int row = wp >> 4, colw = wp & 15;
    const float* im = in + ((size_t)img << 20);
    const int* L = labels + ((size_t)img << 20);
    const int* C = counts + ((size_t)img << 20);
    ull mN  = (row > 0)     ? mask[w - WPR] : 0ull;
    ull mS  = (row < H - 1) ? mask[w + WPR] : 0ull;
    ull mE1 = (colw < 15)   ? mask[w + 1]   : 0ull;
    ull mWw = (colw > 0)    ? mask[w - 1]   : 0ull;
    ull fgE = (m >> 1) | (mE1 << 63);
    ull fgW = (m << 1) | (mWw >> 63);
    ull boundary = m & ~(mN & mS & fgE & fgW);
    int pbase = wp << 6;
    while (boundary) {
        int b = __builtin_ctzll(boundary);
        boundary &= boundary - 1;
        int p = pbase + b;
        int c = C[L[p]];
        if (c <= 21) continue;          // lm == 0 -> out stays 0
        int y = p >> 10, x = p & 1023;

        // directmask at (y,x): 3x3 reflect blur of gradient products
        float sxx = 0.0f, syy = 0.0f, sxy = 0.0f;
        #pragma unroll
        for (int di = -1; di <= 1; ++di) {
            int r = y + di;
            if (r < 0) r = -r;
            if (r >= H) r = 2 * H - 2 - r;
            #pragma unroll
            for (int dj = -1; dj <= 1; ++dj) {
                int cc = x + dj;
                if (cc < 0) cc = -cc;
                if (cc >= W) cc = 2 * W - 2 - cc;
                float gxv = gmz(im, r, cc - 1) - gmz(im, r, cc + 1);
                float gyv = gmz(im, r - 1, cc) - gmz(im, r + 1, cc);
                float txx = gxv * gxv;
                float tyy = gyv * gyv;
                float txy = gxv * gyv;
                sxx = sxx + txx;
                syy = syy + tyy;
                sxy = sxy + txy;
            }
        }
        sxx /= 9.0f; syy /= 9.0f; sxy /= 9.0f;
        float d = sxx - syy;
        float tmp = sqrtf(d * d + 4.0f * (sxy * sxy));
        float dmv = tmp / (sxx + syy + 1e-16f);

        float gc_ = gm_eval(im, y, x);
        float v = gc_ * dmv * (float)c;
        v = fminf(fmaxf(v, 0.0f), 1.0f);
        out[((size_t)img << 20) + p] = v;
    }
}

// ---------------------------------------------------------------- launch
extern "C" void kernel_launch(void* const* d_in, const int* in_sizes, int n_in,
                              void* d_out, int out_size, void* d_ws, size_t ws_size,
                              hipStream_t stream) {
    const float* base = (const float*)d_in[0];
    float* out = (float*)d_out;

    int* labels = (int*)d_ws;
    int* counts = (int*)((char*)d_ws + (size_t)TOT * 4);
    ull* mask   = (ull*)((char*)d_ws + 2ull * (size_t)TOT * 4);

    dim3 gridStrips(NBLK);
    dim3 gridWords(NWORDS / 256);

    gm_kernel<<<gridStrips, dim3(BT), 0, stream>>>(base, out, mask, labels, counts);
    merge_words<<<gridWords, dim3(256), 0, stream>>>(mask, labels);
    count_words<<<gridWords, dim3(256), 0, stream>>>(mask, labels, counts);
    sparse_final<<<gridWords, dim3(256), 0, stream>>>(base, mask, labels, counts, out);
}

// Round 16
// 31.590 us; speedup vs baseline: 1.0713x; 1.0018x over previous
//
#include <hip/hip_runtime.h>

#define H 1024
#define W 1024
#define NPIX (H * W)
#define NIMG 12
#define TOT (NIMG * NPIX)
#define NWORDS (TOT / 64)   /* 196608 fg-mask words (64 px each) */
#define WPR 16              /* mask words per image row */
#define WPI (NPIX / 64)     /* mask words per image */

#define RSTRIP 4                          /* rows per strip */
#define BT 64                             /* gm block threads (1 wave) */
#define NBLK (NIMG * (H / RSTRIP) * 4)    /* 12288 gm blocks (quarter-width) */

typedef unsigned long long ull;

// Constants computed in double then demoted to float, matching Python/JAX.
__device__ __constant__ float C_HALF = (float)(0.5 * (1.0 / 1023.0));
__device__ __constant__ float C_FOUR = (float)(4.0 * (1.0 / 1023.0));
__device__ __constant__ float C_ONE  = (float)(1.0 * (1.0 / 1023.0));
#define SCALE 255.75f  /* 1023/4, exact */

// static component select (folds to a register pick under full unroll)
#define COMP(v, k) ((k) == 0 ? (v).x : (k) == 1 ? (v).y : (k) == 2 ? (v).z : (v).w)

// --------------------------------------------------------------- gm (dense)
// R12 structure (shfl horizontal halos, RSTRIP=4) at 1-wave blocks:
// finest residency backfill granule (time ~ requests / resident-waves).
// Label/count stores skipped at wave granularity when no lane is fg.
__global__ __launch_bounds__(BT) void gm_kernel(const float* __restrict__ in,
                                                float* __restrict__ out,
                                                ull* __restrict__ mask,
                                                int* __restrict__ labels,
                                                int* __restrict__ counts) {
    int bid = blockIdx.x;
    // XCD-chunked swizzle: contiguous blocks stay on one XCD's L2 (12288%8==0)
    int wblk = (bid & 7) * (NBLK / 8) + (bid >> 3);
    int img   = wblk >> 10;           // 1024 blocks per image
    int rem   = wblk & 1023;
    int strip = rem >> 2;
    int xbase = (rem & 3) << 8;       // 0 / 256 / 512 / 768
    int y0 = strip * RSTRIP;
    int t  = threadIdx.x;             // 64 threads: quarter-row of quads
    int x0 = xbase + (t << 2);
    const float* im = in + ((size_t)img << 20);
    float* ob = out + ((size_t)img << 20);
    int* Lb = labels + ((size_t)img << 20);
    int* Cb = counts + ((size_t)img << 20);
    int lane = t;                     // block == one wave
    bool e0  = (lane == 0);
    bool e63 = (lane == 63);

    const float4 z4 = make_float4(0.f, 0.f, 0.f, 0.f);
    float4 win[7];                    // rows y-3 .. y+3 of this column
    #pragma unroll
    for (int j = 0; j < 6; ++j) {
        int yy = y0 - 3 + j;
        win[j] = (yy >= 0 && yy < H) ? *(const float4*)(im + yy * W + x0) : z4;
    }

    #pragma unroll
    for (int i = 0; i < RSTRIP; ++i) {
        int y = y0 + i;
        int yl = y + 3;
        win[6] = (yl < H) ? *(const float4*)(im + yl * W + x0) : z4;
        float4 B = win[3];

        // one predicated load serves both wave-edge lanes (lane0: x0-4,
        // lane63: x0+4); interior lanes get halos via shfl below.
        float4 edge = z4;
        if ((e0 & (x0 >= 4)) | (e63 & (x0 < 1020))) {
            edge = *(const float4*)(im + y * W + (e0 ? x0 - 4 : x0 + 4));
        }
        // left halo: columns x0-3..x0-1 = neighbor lane's B.y/.z/.w
        float Ay = __shfl_up(B.y, 1);
        float Az = __shfl_up(B.z, 1);
        float Aw = __shfl_up(B.w, 1);
        if (e0) { Ay = edge.y; Az = edge.z; Aw = edge.w; }
        // right halo: columns x0+4..x0+6 = neighbor lane's B.x/.y/.z
        float Cx = __shfl_down(B.x, 1);
        float Cy = __shfl_down(B.y, 1);
        float Cz = __shfl_down(B.z, 1);
        if (e63) { Cx = edge.x; Cy = edge.y; Cz = edge.z; }

        // wnd[j] = column x0-4+j (wnd[0]/wnd[11] unused by k=0..3)
        float wnd[12] = {0.0f, Ay, Az, Aw, B.x, B.y, B.z, B.w,
                         Cx, Cy, Cz, 0.0f};

        unsigned nib = 0;
        #pragma unroll
        for (int k = 0; k < 4; ++k) {
            // axis=1 (x): d(k') = col(x-k') - col(x+k'), zero fill
            float g1 = wnd[k + 3] - wnd[k + 5];
            float a = fabsf(g1);
            bool arange = (a <= C_FOUR) & (a > C_ONE);
            float gx = 0.0f;
            if (__any(arange)) {
                float g2 = wnd[k + 2] - wnd[k + 6];
                float g3 = wnd[k + 1] - wnd[k + 7];
                float gmer = (g1 + g2 + g3) / 3.0f;
                bool keep = (fabsf(gmer - g1) <= C_HALF) & arange;
                gx = keep ? a : 0.0f;
            }
            // axis=0 (y)
            g1 = COMP(win[2], k) - COMP(win[4], k);
            a = fabsf(g1);
            arange = (a <= C_FOUR) & (a > C_ONE);
            float gy = 0.0f;
            if (__any(arange)) {
                float g2 = COMP(win[1], k) - COMP(win[5], k);
                float g3 = COMP(win[0], k) - COMP(win[6], k);
                float gmer = (g1 + g2 + g3) / 3.0f;
                bool keep = (fabsf(gmer - g1) <= C_HALF) & arange;
                gy = keep ? a : 0.0f;
            }

            float gmv = fmaxf(gx, gy) * SCALE;
            bool fg = gmv > 1.0f;
            if (__any(fg)) {          // skip store issue when whole wave empty
                if (fg) {
                    int p = y * W + x0 + k;
                    Lb[p] = p;
                    Cb[p] = 0;
                }
            }
            nib |= (unsigned)fg << k;
        }

        // zero output row segment (sparse_final rewrites the few nonzeros)
        *(float4*)(ob + y * W + x0) = z4;

        // mask words via 32-bit butterfly: 8 lanes x 4 bits per 32-bit group,
        // then one cross-halfword shfl to assemble the 64-px word.
        unsigned v32 = nib << ((lane & 7) << 2);
        v32 |= __shfl_xor((int)v32, 1);
        v32 |= __shfl_xor((int)v32, 2);
        v32 |= __shfl_xor((int)v32, 4);
        unsigned hi = (unsigned)__shfl_xor((int)v32, 8);
        if ((lane & 15) == 0) {
            mask[((size_t)img << 14) + (y << 4) + (x0 >> 6)] =
                (ull)v32 | ((ull)hi << 32);
        }

        // slide window
        #pragma unroll
        for (int j = 0; j < 6; ++j) win[j] = win[j + 1];
    }
}

// ------------------------------------------------------------- union-find
__device__ __forceinline__ int find_root(int* L, int a) {
    int l = L[a];
    while (l != a) { a = l; l = L[a]; }
    return a;
}

__device__ __forceinline__ void unite(int* L, int a, int b) {
    while (true) {
        a = find_root(L, a);
        b = find_root(L, b);
        if (a == b) return;
        if (a > b) { int t = a; a = b; b = t; }
        int old = atomicMin(&L[b], a);
        if (old == b) return;
        b = old;
    }
}

// ------------------------------------------- word-based (sparse) CCL kernels
__global__ __launch_bounds__(256) void merge_words(const ull* __restrict__ mask,
                                                   int* __restrict__ labels) {
    int w = blockIdx.x * blockDim.x + threadIdx.x;
    ull m = mask[w];
    if (!m) return;
    int img = w >> 14;
    int wp  = w & (WPI - 1);
    int row = wp >> 4, colw = wp & 15;
    int* L = labels + ((size_t)img << 20);
    bool hasS = row < H - 1, hasE = colw < 15, hasW = colw > 0;
    ull mS   = hasS ? mask[w + WPR] : 0ull;
    ull mE1  = hasE ? mask[w + 1] : 0ull;
    ull mSWw = (hasS && hasW) ? mask[w + WPR - 1] : 0ull;
    ull mSEw = (hasS && hasE) ? mask[w + WPR + 1] : 0ull;
    ull fgE  = (m >> 1) | (mE1 << 63);
    ull fgS  = mS;
    ull fgSW = (mS << 1) | (mSWw >> 63);
    ull fgSE = (mS >> 1) | (mSEw << 63);
    int pbase = wp << 6;
    ull t = m;
    while (t) {
        int b = __builtin_ctzll(t);
        t &= t - 1;
        int p = pbase + b;
        ull bit = 1ull << b;
        if (fgE & bit)  unite(L, p, p + 1);
        if (fgSW & bit) unite(L, p, p + W - 1);
        if (fgS & bit)  unite(L, p, p + W);
        if (fgSE & bit) unite(L, p, p + W + 1);
    }
}

__global__ __launch_bounds__(256) void count_words(const ull* __restrict__ mask,
                                                   int* __restrict__ labels,
                                                   int* __restrict__ counts) {
    int w = blockIdx.x * blockDim.x + threadIdx.x;
    ull m = mask[w];
    if (!m) return;
    int img = w >> 14;
    int wp  = w & (WPI - 1);
    int row = wp >> 4, colw = wp & 15;
    int* L = labels + ((size_t)img << 20);
    int* C = counts + ((size_t)img << 20);
    ull mN  = (row > 0)     ? mask[w - WPR] : 0ull;
    ull mS  = (row < H - 1) ? mask[w + WPR] : 0ull;
    ull mE1 = (colw < 15)   ? mask[w + 1]   : 0ull;
    ull mWw = (colw > 0)    ? mask[w - 1]   : 0ull;
    ull fgE = (m >> 1) | (mE1 << 63);
    ull fgW = (m << 1) | (mWw >> 63);
    ull boundary = m & ~(mN & mS & fgE & fgW);
    int pbase = wp << 6;
    while (boundary) {
        int b = __builtin_ctzll(boundary);
        boundary &= boundary - 1;
        int p = pbase + b;
        int r = find_root(L, p);
        L[p] = r;                 // flatten boundary pixels (read by final)
        atomicAdd(&C[r], 1);
    }
}

// --------------------------------------------------- sparse final (dm eval)
// Recompute gm bitwise-identically at (y,x); zero-fill at image edges.
__device__ float gm_eval(const float* __restrict__ im, int y, int x) {
    int p = y * W + x;
    float xm1 = (x >= 1)     ? im[p - 1] : 0.0f;
    float xp1 = (x < W - 1)  ? im[p + 1] : 0.0f;
    float xm2 = (x >= 2)     ? im[p - 2] : 0.0f;
    float xp2 = (x < W - 2)  ? im[p + 2] : 0.0f;
    float xm3 = (x >= 3)     ? im[p - 3] : 0.0f;
    float xp3 = (x < W - 3)  ? im[p + 3] : 0.0f;
    float g1 = xm1 - xp1;
    float g2 = xm2 - xp2;
    float g3 = xm3 - xp3;
    float gmer = (g1 + g2 + g3) / 3.0f;
    float a = fabsf(g1);
    bool keep = (fabsf(gmer - g1) <= C_HALF) & (a <= C_FOUR) & (a > C_ONE);
    float gx = keep ? a : 0.0f;

    float ym1 = (y >= 1)    ? im[p - W]     : 0.0f;
    float yp1 = (y < H - 1) ? im[p + W]     : 0.0f;
    float ym2 = (y >= 2)    ? im[p - 2 * W] : 0.0f;
    float yp2 = (y < H - 2) ? im[p + 2 * W] : 0.0f;
    float ym3 = (y >= 3)    ? im[p - 3 * W] : 0.0f;
    float yp3 = (y < H - 3) ? im[p + 3 * W] : 0.0f;
    g1 = ym1 - yp1;
    g2 = ym2 - yp2;
    g3 = ym3 - yp3;
    gmer = (g1 + g2 + g3) / 3.0f;
    a = fabsf(g1);
    keep = (fabsf(gmer - g1) <= C_HALF) & (a <= C_FOUR) & (a > C_ONE);
    float gy = keep ? a : 0.0f;

    return fmaxf(gx, gy) * SCALE;
}

__device__ __forceinline__ float gmz(const float* __restrict__ im, int y, int x) {
    if ((unsigned)y >= H || (unsigned)x >= W) return 0.0f;  // zero fill
    return gm_eval(im, y, x);
}

__global__ __launch_bounds__(256) void sparse_final(const float* __restrict__ in,
                                                    const ull* __restrict__ mask,
                                                    const int* __restrict__ labels,
                                                    const int* __restrict__ counts,
                                                    float* __restrict__ out) {
    #pragma clang fp contract(off)
    int w = blockIdx.x * blockDim.x + threadIdx.x;
    ull m = mask[w];
    if (!m) return;
    int img = w >> 14;
    int wp  = w & (WPI - 1);
    int row = wp >> 4, colw = wp & 15;
    const float* im = in + ((size_t)img << 20);
    const int* L = labels + ((size_t)img << 20);
    const int* C = counts + ((size_t)img << 20);
    ull mN  = (row > 0)     ? mask[w - WPR] : 0ull;
    ull mS  = (row < H - 1) ? mask[w + WPR] : 0ull;
    ull mE1 = (colw < 15)   ? mask[w + 1]   : 0ull;
    ull mWw = (colw > 0)    ? mask[w - 1]   : 0ull;
    ull fgE = (m >> 1) | (mE1 << 63);
    ull fgW = (m << 1) | (mWw >> 63);
    ull boundary = m & ~(mN & mS & fgE & fgW);
    int pbase = wp << 6;
    while (boundary) {
        int b = __builtin_ctzll(boundary);
        boundary &= boundary - 1;
        int p = pbase + b;
        int c = C[L[p]];
        if (c <= 21) continue;          // lm == 0 -> out stays 0
        int y = p >> 10, x = p & 1023;

        // directmask at (y,x): 3x3 reflect blur of gradient products
        float sxx = 0.0f, syy = 0.0f, sxy = 0.0f;
        #pragma unroll
        for (int di = -1; di <= 1; ++di) {
            int r = y + di;
            if (r < 0) r = -r;
            if (r >= H) r = 2 * H - 2 - r;
            #pragma unroll
            for (int dj = -1; dj <= 1; ++dj) {
                int cc = x + dj;
                if (cc < 0) cc = -cc;
                if (cc >= W) cc = 2 * W - 2 - cc;
                float gxv = gmz(im, r, cc - 1) - gmz(im, r, cc + 1);
                float gyv = gmz(im, r - 1, cc) - gmz(im, r + 1, cc);
                float txx = gxv * gxv;
                float tyy = gyv * gyv;
                float txy = gxv * gyv;
                sxx = sxx + txx;
                syy = syy + tyy;
                sxy = sxy + txy;
            }
        }
        sxx /= 9.0f; syy /= 9.0f; sxy /= 9.0f;
        float d = sxx - syy;
        float tmp = sqrtf(d * d + 4.0f * (sxy * sxy));
        float dmv = tmp / (sxx + syy + 1e-16f);

        float gc_ = gm_eval(im, y, x);
        float v = gc_ * dmv * (float)c;
        v = fminf(fmaxf(v, 0.0f), 1.0f);
        out[((size_t)img << 20) + p] = v;
    }
}

// ---------------------------------------------------------------- launch
extern "C" void kernel_launch(void* const* d_in, const int* in_sizes, int n_in,
                              void* d_out, int out_size, void* d_ws, size_t ws_size,
                              hipStream_t stream) {
    const float* base = (const float*)d_in[0];
    float* out = (float*)d_out;

    int* labels = (int*)d_ws;
    int* counts = (int*)((char*)d_ws + (size_t)TOT * 4);
    ull* mask   = (ull*)((char*)d_ws + 2ull * (size_t)TOT * 4);

    dim3 gridStrips(NBLK);
    dim3 gridWords(NWORDS / 256);

    gm_kernel<<<gridStrips, dim3(BT), 0, stream>>>(base, out, mask, labels, counts);
    merge_words<<<gridWords, dim3(256), 0, stream>>>(mask, labels);
    count_words<<<gridWords, dim3(256), 0, stream>>>(mask, labels, counts);
    sparse_final<<<gridWords, dim3(256), 0, stream>>>(base, mask, labels, counts, out);
}